// Round 13
// baseline (1721.111 us; speedup 1.0000x reference)
//
#include <hip/hip_runtime.h>

typedef unsigned short u16;
typedef short s16x8 __attribute__((ext_vector_type(8)));   // 8 bf16 bit-patterns
typedef float f32x4 __attribute__((ext_vector_type(4)));

#define DI __device__ __forceinline__

constexpr int N_ = 50000;
constexpr int E_ = 400000;
constexpr int G_ = 64;
constexpr int MS_ = 112;            // msg row stride in u16 (224 B)
constexpr int EPB_ = 480;           // edges per block (15 consumer waves x 32)

DI u16 f2bf(float f) {
    union { unsigned u; float f; } c; c.f = f;
    unsigned u = c.u;
    u += 0x7fffu + ((u >> 16) & 1u);   // RNE
    return (u16)(u >> 16);
}
DI float bf2f(u16 v) {
    union { unsigned u; float f; } c; c.u = (unsigned)v << 16;
    return c.f;
}
DI unsigned pkbf(float lo, float hi) {   // u32 = bf16(lo) | bf16(hi)<<16 (RNE)
    return (unsigned)f2bf(lo) | ((unsigned)f2bf(hi) << 16);
}

DI s16x8 ldv(const u16* p) { return *(const s16x8*)p; }
DI f32x4 MFMA(s16x8 a, s16x8 b, f32x4 c) {
    return __builtin_amdgcn_mfma_f32_16x16x32_bf16(a, b, c, 0, 0, 0);
}

// ---------------------------------------------------------------------------
// PRODUCER-WAVE staging, plain loads (L2/L3-cached path), transient batches
// of 10 int4 (40 VGPRs, never live across MFMA -> no R9 spill).
// R8-R12 synthesis: ANY stage-once-per-block scheme pays blocks x 420 KB of
// L2-miss traffic at the ~3 TB/s L3 ceiling (FETCH == that volume in every
// staging round; dur == bytes/3TB/s). The only lever is VOLUME -> this
// round: 16-wave blocks (480 edges) -> 834 blocks x 420 KB = 350 MB.
// ---------------------------------------------------------------------------
template<int BYTES>
DI void stage_p(const u16* __restrict__ g, u16* l, int lane) {
    constexpr int ITER = BYTES / 1024;          // 64 lanes x 16 B per iter
    #pragma unroll
    for (int base = 0; base < ITER; base += 10) {
        int4 t[10];
        #pragma unroll
        for (int i = 0; i < 10; ++i)
            if (base + i < ITER)
                t[i] = *(const int4*)(g + ((base + i) << 9) + lane * 8);
        #pragma unroll
        for (int i = 0; i < 10; ++i)
            if (base + i < ITER)
                *(int4*)(l + ((base + i) << 9) + lane * 8) = t[i];
    }
}

// ---------------------------------------------------------------------------
// C-frag pair (transposed GEMM output: rows=channels, cols=edges) -> next
// GEMM's B-frag (lane&15=edge, k=kq*8+j), fused ReLU. 8 pkbf + 8
// ds_bpermute + 4 selects, no LDS storage. Verified vs C/D layout
// col=lane&15,row=kq*4+r (m89).
// ---------------------------------------------------------------------------
DI s16x8 conv_frag(const f32x4 a0, const f32x4 a1, int kq, int col) {
    unsigned c0 = pkbf(fmaxf(a0[0], 0.f), fmaxf(a0[1], 0.f));
    unsigned c1 = pkbf(fmaxf(a0[2], 0.f), fmaxf(a0[3], 0.f));
    unsigned c2 = pkbf(fmaxf(a1[0], 0.f), fmaxf(a1[1], 0.f));
    unsigned c3 = pkbf(fmaxf(a1[2], 0.f), fmaxf(a1[3], 0.f));
    int aA = (kq & 1) * 128 + col * 4;       // src lane (kq&1)*32 + col
    int aB = aA + 64;                        // src lane (kq&1)*32 + 16 + col
    unsigned A0 = __builtin_amdgcn_ds_bpermute(aA, (int)c0);
    unsigned A1 = __builtin_amdgcn_ds_bpermute(aA, (int)c1);
    unsigned A2 = __builtin_amdgcn_ds_bpermute(aA, (int)c2);
    unsigned A3 = __builtin_amdgcn_ds_bpermute(aA, (int)c3);
    unsigned B0 = __builtin_amdgcn_ds_bpermute(aB, (int)c0);
    unsigned B1 = __builtin_amdgcn_ds_bpermute(aB, (int)c1);
    unsigned B2 = __builtin_amdgcn_ds_bpermute(aB, (int)c2);
    unsigned B3 = __builtin_amdgcn_ds_bpermute(aB, (int)c3);
    bool hi = (kq >> 1) != 0;
    union { unsigned u[4]; s16x8 v; } o;
    o.u[0] = hi ? A2 : A0;
    o.u[1] = hi ? A3 : A1;
    o.u[2] = hi ? B2 : B0;
    o.u[3] = hi ? B3 : B1;
    return o.v;
}

// ---------------------------------------------------------------------------
// Named kernel: zero hist + repack weights f32 -> bf16 in fragment-order
// sections, LANE-LINEAR inside each section (wave ds_read_b128 of a section
// = contiguous 1024 B, conflict-free). Folds [xi, xj-xi] @ W =
// xi @ (W_a - W_b) + xj @ W_b and biases into K-pad rows (input slot 1.0).
// ---------------------------------------------------------------------------
__global__ __launch_bounds__(256)
void ModelGNN_35304631174019_kernel(
          const float* __restrict__ l0w1, const float* __restrict__ l0w2,
          const float* __restrict__ l0w3, const float* __restrict__ l1w1,
          const float* __restrict__ l1w2, const float* __restrict__ l1w3,
          const float* __restrict__ l0b1, const float* __restrict__ l0b2,
          const float* __restrict__ l0b3, const float* __restrict__ l1b1,
          const float* __restrict__ l1b2, const float* __restrict__ l1b3,
          float4* __restrict__ histz,
          u16* __restrict__ wt0, u16* __restrict__ wt1,
          u16* __restrict__ wt2a, u16* __restrict__ wt2b,
          u16* __restrict__ wt3a, u16* __restrict__ wt3b)
{
    int i = blockIdx.x * 256 + threadIdx.x;
    if (i < 12500) { histz[i] = make_float4(0.f, 0.f, 0.f, 0.f); return; }
    int f = i - 12500;

    if (f < 10240) {                       // wt0: layer0 W1, KP=32 (KA=1)
        int sec = f >> 9, w = f & 511;
        int ln = w >> 3, j = w & 7;
        int col = ln & 15, kq = ln >> 4;
        int n0c = sec >> 1, b01 = sec & 1;
        int n = n0c * 32 + b01 * 16 + col, k = kq * 8 + j;
        u16 v = 0;
        if (n < 300) {
            if (k < 7)                  v = f2bf(l0w1[k * 300 + n] - l0w1[(7 + k) * 300 + n]);
            else if (k >= 16 && k < 23) v = f2bf(l0w1[(7 + (k - 16)) * 300 + n]);
            else if (k == 15)           v = f2bf(l0b1[n]);
        }
        wt0[f] = v; return;
    }
    f -= 10240;
    if (f < 71680) {                       // wt1: layer1 W1, KP=224 (KA=7)
        int sec = f >> 9, w = f & 511;
        int ln = w >> 3, j = w & 7;
        int col = ln & 15, kq = ln >> 4;
        int n0c = sec / 14, r = sec % 14;
        int s = r >> 1, b01 = r & 1;
        int n = n0c * 32 + b01 * 16 + col, k = s * 32 + kq * 8 + j;
        u16 v = 0;
        if (n < 300) {
            if (k < 100)                  v = f2bf(l1w1[k * 300 + n] - l1w1[(100 + k) * 300 + n]);
            else if (k >= 112 && k < 212) v = f2bf(l1w1[(100 + (k - 112)) * 300 + n]);
            else if (k == 100)            v = f2bf(l1b1[n]);
        }
        wt1[f] = v; return;
    }
    f -= 71680;
    if (f < 204800) {                      // wt2a / wt2b: 300x300, K=320 (KA=10)
        const float* src = (f < 102400) ? l0w2 : l1w2;
        const float* bia = (f < 102400) ? l0b2 : l1b2;
        u16* dst = (f < 102400) ? wt2a : wt2b;
        int f2 = (f < 102400) ? f : f - 102400;
        int sec = f2 >> 9, w = f2 & 511;
        int ln = w >> 3, j = w & 7;
        int col = ln & 15, kq = ln >> 4;
        int n0c = sec / 20, r = sec % 20;
        int s = r >> 1, b01 = r & 1;
        int n = n0c * 32 + b01 * 16 + col, k = s * 32 + kq * 8 + j;
        u16 v = 0;
        if (n < 300) {
            if (k < 300)       v = f2bf(src[k * 300 + n]);
            else if (k == 300) v = f2bf(bia[n]);
        }
        dst[f2] = v;
        return;
    }
    f -= 204800;
    if (f < 71680) {                       // wt3a / wt3b: 300x100 -> [112 n3][320 k]
        const float* src = (f < 35840) ? l0w3 : l1w3;
        const float* bia = (f < 35840) ? l0b3 : l1b3;
        u16* dst = (f < 35840) ? wt3a : wt3b;
        int f2 = (f < 35840) ? f : f - 35840;
        int sec = f2 >> 9, w = f2 & 511;
        int ln = w >> 3, j = w & 7;
        int col = ln & 15, kq = ln >> 4;
        int ch = sec / 7, u = sec % 7;
        int n3 = u * 16 + col, k = ch * 32 + kq * 8 + j;
        u16 v = 0;
        if (n3 < 100) {
            if (k < 300)       v = f2bf(src[k * 100 + n3]);
            else if (k == 300) v = f2bf(bia[n3]);
        }
        dst[f2] = v;
        return;
    }
}

// ---------------------------------------------------------------------------
// Count-sort edges by dst: hist -> exclusive scan -> scatter-fill.
// ---------------------------------------------------------------------------
__global__ __launch_bounds__(256)
void hist_k(const int* __restrict__ ei, int* __restrict__ hist)
{
    int i = blockIdx.x * 256 + threadIdx.x;
    if (i < E_) atomicAdd(&hist[ei[E_ + i]], 1);
}

__global__ __launch_bounds__(1024)
void scan_k(int* h)   // in-place exclusive scan of h[50000], single block
{
    __shared__ int part[1024];
    const int t = threadIdx.x;
    const int CH = 49;
    int base = t * CH;
    int end = base + CH; if (end > 50000) end = 50000;
    int s = 0;
    for (int i = base; i < end; ++i) s += h[i];
    part[t] = s;
    __syncthreads();
    for (int d = 1; d < 1024; d <<= 1) {
        int v = (t >= d) ? part[t - d] : 0;
        __syncthreads();
        part[t] += v;
        __syncthreads();
    }
    int run = (t ? part[t - 1] : 0);
    for (int i = base; i < end; ++i) { int c = h[i]; h[i] = run; run += c; }
}

__global__ __launch_bounds__(256)
void fill_k(const int* __restrict__ ei, int* __restrict__ pos, int* __restrict__ sei)
{
    int i = blockIdx.x * 256 + threadIdx.x;
    if (i >= E_) return;
    int s = ei[i], d = ei[E_ + i];
    int p = atomicAdd(&pos[d], 1);
    sei[p] = s; sei[E_ + p] = d;
}

// ---------------------------------------------------------------------------
// edge_mlp R22: 16-WAVE producer-consumer blocks (1024 threads).
// wave 15 = producer (entire weight stream, batched plain loads ->
// ds_write); waves 0-14 = consumers (32 edges each = 480/block, pure
// ds_read + MFMA + conv_frag). Grid 834 -> weight L2-miss volume 350 MB
// (R12: 750 MB -> was the ~3 TB/s L3-ceiling bound). 1 block/CU but
// 16 waves/CU = 50% occupancy. Choreography identical to R12 (verified).
// ---------------------------------------------------------------------------
template<bool FIRST>
__global__ __launch_bounds__(1024, 1)
void edge_mlp(const float* __restrict__ X, const float* __restrict__ H0,
              const int* __restrict__ ei,
              const u16* __restrict__ W1, const u16* __restrict__ W2,
              const u16* __restrict__ W3,
              u16* __restrict__ msg)
{
    constexpr int KA = FIRST ? 1 : 7;
    // SH: WL0 [0,13824) | WL1 [13824,27648) | SCR [27648, 27648+19200)
    // epilogue MOUT reuses SH from 0: 15 waves x 3584 u16 = 53,760 u16
    __shared__ __align__(16) u16 SH[53760];           // 107,520 B -> 1 blk/CU

    const int tid  = threadIdx.x;
    const int wave = tid >> 6, lane = tid & 63;
    const int col  = lane & 15, kq = lane >> 4;
    const bool prod = (wave == 15);
    const int ebase = blockIdx.x * EPB_ + wave * 32;  // consumers: 32 edges
    const int fragoff = lane * 8;                     // lane-linear sections

    u16* WL0 = SH;
    u16* WL1 = SH + 13824;
    u16* SCw = SH + 27648 + wave * (32 * 40);         // waves 0..14 only

    // ---- prologue: producer stages, consumers build input fragments ----
    s16x8 aF[2][KA];
    if (prod) {
        if constexpr (FIRST) {
            stage_p<20480>(W1, WL0, lane);            // all of wt0
            stage_p<20480>(W2, WL1, lane);            // G23 c0
            stage_p<7168>(W3, WL1 + 10240, lane);
        } else {
            stage_p<14336>(W1, WL0, lane);            // W1 c0
        }
    } else {
        if constexpr (FIRST) {
            // gather [xi | 1 | xj] for 32 edges into SCw as bf16 IN[32][40]
            for (int s = lane; s < 32 * 32; s += 64) {
                int e = s >> 5, k = s & 31;
                int eidx = ebase + e; if (eidx >= E_) eidx = E_ - 1;  // clamp
                u16 v = 0;
                if (k < 7)                  v = f2bf(X[(size_t)ei[E_ + eidx] * 7 + k]);
                else if (k >= 16 && k < 23) v = f2bf(X[(size_t)ei[eidx] * 7 + (k - 16)]);
                else if (k == 15)           v = 0x3f80;   // bias slot: 1.0
                SCw[e * 40 + k] = v;
            }
            #pragma unroll
            for (int rt = 0; rt < 2; ++rt)
                aF[rt][0] = ldv(SCw + (rt * 16 + col) * 40 + kq * 8);
        } else {
            #pragma unroll
            for (int rt = 0; rt < 2; ++rt) {
                int eidx = ebase + rt * 16 + col; if (eidx >= E_) eidx = E_ - 1;
                const int dn = ei[E_ + eidx];          // x_i
                const int sn = ei[eidx];               // x_j
                #pragma unroll
                for (int s = 0; s < KA; ++s) {
                    int b = s * 4 + kq;            // 8-elem k-group; k = 8b+j
                    int node = (b < 14) ? dn : sn;
                    int c = ((b < 14) ? b : b - 14) * 8;
                    s16x8 t = {0, 0, 0, 0, 0, 0, 0, 0};
                    if (c < 104) {
                        const float* r = H0 + (size_t)node * 100 + c;
                        float4 lo = *(const float4*)r;
                        t[0] = (short)f2bf(lo.x); t[1] = (short)f2bf(lo.y);
                        t[2] = (short)f2bf(lo.z); t[3] = (short)f2bf(lo.w);
                        if (c < 96) {
                            float4 hi = *(const float4*)(r + 4);
                            t[4] = (short)f2bf(hi.x); t[5] = (short)f2bf(hi.y);
                            t[6] = (short)f2bf(hi.z); t[7] = (short)f2bf(hi.w);
                        }
                    }
                    if (s == 3 && kq == 0) t[4] = (short)0x3f80;  // k=100 bias
                    aF[rt][s] = t;
                }
            }
        }
    }
    __syncthreads();   // prologue staging + gathers landed

    // ---- GEMM1: H1^T chunks -> in-register conv -> a2 B-fragments ----
    s16x8 a2[2][10];
    if constexpr (FIRST) {
        if (!prod) {
            #pragma unroll 1
            for (int t2 = 0; t2 < 10; ++t2) {
                const u16* w0 = WL0 + (t2 * 2) * 512 + fragoff;
                f32x4 z = {0.f, 0.f, 0.f, 0.f};
                f32x4 ac[2][2] = {{z, z}, {z, z}};    // [cb][rt]
                s16x8 b0 = ldv(w0);
                s16x8 b1 = ldv(w0 + 512);
                #pragma unroll
                for (int rt = 0; rt < 2; ++rt) {
                    ac[0][rt] = MFMA(b0, aF[rt][0], ac[0][rt]);
                    ac[1][rt] = MFMA(b1, aF[rt][0], ac[1][rt]);
                }
                #pragma unroll
                for (int rt = 0; rt < 2; ++rt)
                    a2[rt][t2] = conv_frag(ac[0][rt], ac[1][rt], kq, col);
            }
        }
        __syncthreads();   // WL0 free before G23 c1 stages into it
    } else {
        #pragma unroll 1
        for (int t2 = 0; t2 < 10; ++t2) {
            if (prod) {
                if (t2 < 9)
                    stage_p<14336>(W1 + (size_t)(t2 + 1) * 14 * 512,
                                   (t2 & 1) ? WL0 : WL1, lane);
                else {     // stage G23 c0 into WL0 (read at ch=0)
                    stage_p<20480>(W2, WL0, lane);
                    stage_p<7168>(W3, WL0 + 10240, lane);
                }
            } else {
                const u16* w0 = ((t2 & 1) ? WL1 : WL0) + fragoff;
                f32x4 z = {0.f, 0.f, 0.f, 0.f};
                f32x4 ac[2][2] = {{z, z}, {z, z}};
                #pragma unroll
                for (int s = 0; s < KA; ++s) {
                    s16x8 b0 = ldv(w0 + (2 * s) * 512);
                    s16x8 b1 = ldv(w0 + (2 * s + 1) * 512);
                    #pragma unroll
                    for (int rt = 0; rt < 2; ++rt) {
                        ac[0][rt] = MFMA(b0, aF[rt][s], ac[0][rt]);
                        ac[1][rt] = MFMA(b1, aF[rt][s], ac[1][rt]);
                    }
                }
                #pragma unroll
                for (int rt = 0; rt < 2; ++rt)
                    a2[rt][t2] = conv_frag(ac[0][rt], ac[1][rt], kq, col);
            }
            __syncthreads();                          // next chunk ready
        }
    }
    if (!prod && kq == 1) {                           // GEMM2 k=300 bias slot
        a2[0][9][4] = (short)0x3f80;
        a2[1][9][4] = (short)0x3f80;
    }

    f32x4 mac[2][7];
    #pragma unroll
    for (int rt = 0; rt < 2; ++rt)
        #pragma unroll
        for (int u = 0; u < 7; ++u) { f32x4 z = {0.f, 0.f, 0.f, 0.f}; mac[rt][u] = z; }

    // ---- GEMM2 (K=320) fused with GEMM3, double-buffered chunks ----
    // FIRST: c0 in WL1 -> cur = (ch&1)?WL0:WL1, stage -> (ch&1)?WL1:WL0
    // layer1: c0 in WL0 -> cur = (ch&1)?WL1:WL0, stage -> (ch&1)?WL0:WL1
    #pragma unroll 1
    for (int ch = 0; ch < 10; ++ch) {
        const bool curIs1 = FIRST ? ((ch & 1) == 0) : ((ch & 1) == 1);
        if (prod) {
            if (ch < 9) {
                u16* dst = curIs1 ? WL0 : WL1;
                stage_p<20480>(W2 + (size_t)(ch + 1) * 20 * 512, dst, lane);
                stage_p<7168>(W3 + (size_t)(ch + 1) * 7 * 512, dst + 10240, lane);
            }
        } else {
            const u16* slot = curIs1 ? WL1 : WL0;
            const u16* w0 = slot + fragoff;
            f32x4 z = {0.f, 0.f, 0.f, 0.f};
            f32x4 ac[2][2] = {{z, z}, {z, z}};
            #pragma unroll
            for (int s = 0; s < 10; ++s) {
                s16x8 b0 = ldv(w0 + (2 * s) * 512);
                s16x8 b1 = ldv(w0 + (2 * s + 1) * 512);
                #pragma unroll
                for (int rt = 0; rt < 2; ++rt) {
                    ac[0][rt] = MFMA(b0, a2[rt][s], ac[0][rt]);
                    ac[1][rt] = MFMA(b1, a2[rt][s], ac[1][rt]);
                }
            }
            s16x8 a3[2];
            #pragma unroll
            for (int rt = 0; rt < 2; ++rt)
                a3[rt] = conv_frag(ac[0][rt], ac[1][rt], kq, col);
            if (ch == 9 && kq == 1) {                 // GEMM3 k=300 bias slot
                a3[0][4] = (short)0x3f80;
                a3[1][4] = (short)0x3f80;
            }
            #pragma unroll
            for (int u = 0; u < 7; ++u) {
                s16x8 b3 = ldv(slot + 10240 + u * 512 + fragoff);
                mac[0][u] = MFMA(b3, a3[0], mac[0][u]);
                mac[1][u] = MFMA(b3, a3[1], mac[1][u]);
            }
        }
        __syncthreads();                              // next chunk ready
    }

    // ---- epilogue (consumers): pack relu'd pairs to freed SH [32][112]
    //      per wave, then coalesced 16B-lane global stores (tail-guarded) ----
    if (!prod) {
        u16* MOUT = SH + wave * 3584;                 // 7,168 B per wave
        #pragma unroll
        for (int rt = 0; rt < 2; ++rt) {
            const int row = rt * 16 + col;
            #pragma unroll
            for (int u = 0; u < 7; ++u) {
                unsigned p0 = pkbf(fmaxf(mac[rt][u][0], 0.f), fmaxf(mac[rt][u][1], 0.f));
                unsigned p1 = pkbf(fmaxf(mac[rt][u][2], 0.f), fmaxf(mac[rt][u][3], 0.f));
                int chb = u * 16 + kq * 4;
                *(unsigned*)(MOUT + row * MS_ + chb)     = p0;
                *(unsigned*)(MOUT + row * MS_ + chb + 2) = p1;
            }
        }
        // wave-private region: lgkmcnt ordering only
        const size_t gbase = (size_t)ebase * MS_;
        const size_t glim  = (size_t)E_ * MS_;
        u16* gdst = msg + gbase;
        #pragma unroll
        for (int q = 0; q < 7; ++q) {
            int off = q * 512 + lane * 8;
            s16x8 v = ldv(MOUT + off);
            if (gbase + off < glim)                   // tail-block guard
                *(s16x8*)(gdst + off) = v;
        }
    }
}

// ---------------------------------------------------------------------------
// reduce_k: segment-max over sorted msg runs (stride MS_). One wave per node.
// ---------------------------------------------------------------------------
__global__ __launch_bounds__(256)
void reduce_k(const u16* __restrict__ msg, const int* __restrict__ pos,
              float* __restrict__ agg)
{
    const int n = blockIdx.x * 4 + (threadIdx.x >> 6);
    if (n >= N_) return;
    const int lane = threadIdx.x & 63;
    const int start = n ? pos[n - 1] : 0;
    const int end   = pos[n];
    float m0 = 0.f, m1 = 0.f;
    for (int e = start; e < end; ++e) {
        const u16* row = msg + (size_t)e * MS_;
        m0 = fmaxf(m0, bf2f(row[lane]));
        if (lane < 36) m1 = fmaxf(m1, bf2f(row[64 + lane]));
    }
    agg[(size_t)n * 100 + lane] = m0;
    if (lane < 36) agg[(size_t)n * 100 + 64 + lane] = m1;
}

// ---------------------------------------------------------------------------
// pool: one block per graph (batch sorted -> binary-search bounds).
// ---------------------------------------------------------------------------
__global__ __launch_bounds__(256)
void pool(const float* __restrict__ agg1, const int* __restrict__ batch,
          const float* __restrict__ u, float* __restrict__ pooled)
{
    const int g = blockIdx.x;
    int lo = 0, hi = N_;
    while (lo < hi) { int mid = (lo + hi) >> 1; if (batch[mid] < g) lo = mid + 1; else hi = mid; }
    const int start = lo;
    int lo2 = start, hi2 = N_;
    while (lo2 < hi2) { int mid = (lo2 + hi2) >> 1; if (batch[mid] < g + 1) lo2 = mid + 1; else hi2 = mid; }
    const int end = lo2;

    const int c = threadIdx.x & 127, half = threadIdx.x >> 7;
    float sm = 0.f, mx = 0.f;
    if (c < 100)
        for (int n = start + half; n < end; n += 2) {
            float v = agg1[(size_t)n * 100 + c];
            sm += v; mx = fmaxf(mx, v);
        }
    __shared__ float ssum[128], smax[128];
    if (half) { ssum[c] = sm; smax[c] = mx; }
    __syncthreads();
    if (!half && c < 100) {
        sm += ssum[c]; mx = fmaxf(mx, smax[c]);
        int cnt = end - start;
        pooled[g * 302 + c]       = sm;
        pooled[g * 302 + 100 + c] = sm / fmaxf((float)cnt, 1.f);
        pooled[g * 302 + 200 + c] = mx;
    }
    if (threadIdx.x == 0) {
        pooled[g * 302 + 300] = u[g * 2];
        pooled[g * 302 + 301] = u[g * 2 + 1];
    }
}

// ---------------------------------------------------------------------------
// final 302 -> 100 -> 100 -> 2 MLP, one block per graph, fp32
// ---------------------------------------------------------------------------
__global__ __launch_bounds__(128)
void final_mlp(const float* __restrict__ pooled,
               const float* __restrict__ w1, const float* __restrict__ b1,
               const float* __restrict__ w2, const float* __restrict__ b2,
               const float* __restrict__ w3, const float* __restrict__ b3,
               float* __restrict__ out)
{
    const int g = blockIdx.x, t = threadIdx.x;
    __shared__ float P[302], T1[100], T2[100];
    for (int i = t; i < 302; i += 128) P[i] = pooled[g * 302 + i];
    __syncthreads();
    if (t < 100) {
        float a = b1[t];
        for (int i = 0; i < 302; ++i) a = fmaf(P[i], w1[i * 100 + t], a);
        T1[t] = fmaxf(a, 0.f);
    }
    __syncthreads();
    if (t < 100) {
        float a = b2[t];
        for (int i = 0; i < 100; ++i) a = fmaf(T1[i], w2[i * 100 + t], a);
        T2[t] = fmaxf(a, 0.f);
    }
    __syncthreads();
    if (t < 2) {
        float a = b3[t];
        for (int i = 0; i < 100; ++i) a = fmaf(T2[i], w3[i * 2 + t], a);
        out[g * 2 + t] = a;
    }
}

// ---------------------------------------------------------------------------
extern "C" void kernel_launch(void* const* d_in, const int* in_sizes, int n_in,
                              void* d_out, int out_size, void* d_ws, size_t ws_size,
                              hipStream_t stream)
{
    const float* x     = (const float*)d_in[0];
    const int*   ei    = (const int*)d_in[1];
    const int*   batch = (const int*)d_in[2];
    const float* uu    = (const float*)d_in[3];
    const float *l0w1 = (const float*)d_in[4],  *l0b1 = (const float*)d_in[5];
    const float *l0w2 = (const float*)d_in[6],  *l0b2 = (const float*)d_in[7];
    const float *l0w3 = (const float*)d_in[8],  *l0b3 = (const float*)d_in[9];
    const float *l1w1 = (const float*)d_in[10], *l1b1 = (const float*)d_in[11];
    const float *l1w2 = (const float*)d_in[12], *l1b2 = (const float*)d_in[13];
    const float *l1w3 = (const float*)d_in[14], *l1b3 = (const float*)d_in[15];
    const float *lw1  = (const float*)d_in[16], *lb1  = (const float*)d_in[17];
    const float *lw2  = (const float*)d_in[18], *lb2  = (const float*)d_in[19];
    const float *lw3  = (const float*)d_in[20], *lb3  = (const float*)d_in[21];

    char* w = (char*)d_ws;
    float* agg0   = (float*)(w);                    // 20,000,000 B
    float* agg1   = (float*)(w + 20000000);         // 20,000,000 B
    float* pooled = (float*)(w + 40000000);         //     77,312 B
    u16* wt0  = (u16*)(w + 40077312);               //     20,480 B
    u16* wt1  = (u16*)(w + 40097792);               //    143,360 B
    u16* wt2a = (u16*)(w + 40241152);               //    204,800 B
    u16* wt2b = (u16*)(w + 40445952);               //    204,800 B
    u16* wt3a = (u16*)(w + 40650752);               //     71,680 B
    u16* wt3b = (u16*)(w + 40722432);               //     71,680 B
    int* hist = (int*)(w + 40794112);               //    200,000 B (hist -> run ends)
    int* sei  = (int*)(w + 40994112);               //  3,200,000 B (sorted [src|dst])
    u16* msg  = (u16*)(w + 44194112);               // 89,600,000 B (msgs, 224 B rows)
                                                    // total ~127.6 MiB

    ModelGNN_35304631174019_kernel<<<1449, 256, 0, stream>>>(
        l0w1, l0w2, l0w3, l1w1, l1w2, l1w3,
        l0b1, l0b2, l0b3, l1b1, l1b2, l1b3,
        (float4*)hist, wt0, wt1, wt2a, wt2b, wt3a, wt3b);
    hist_k<<<1563, 256, 0, stream>>>(ei, hist);
    scan_k<<<1, 1024, 0, stream>>>(hist);
    fill_k<<<1563, 256, 0, stream>>>(ei, hist, sei);
    edge_mlp<true ><<<834, 1024, 0, stream>>>(x, nullptr, sei, wt0, wt2a, wt3a, msg);
    reduce_k<<<12500, 256, 0, stream>>>(msg, hist, agg0);
    edge_mlp<false><<<834, 1024, 0, stream>>>(nullptr, agg0, sei, wt1, wt2b, wt3b, msg);
    reduce_k<<<12500, 256, 0, stream>>>(msg, hist, agg1);
    pool<<<G_, 256, 0, stream>>>(agg1, batch, uu, pooled);
    final_mlp<<<G_, 128, 0, stream>>>(pooled, lw1, lb1, lw2, lb2, lw3, lb3, (float*)d_out);
}

// Round 14
// 1383.715 us; speedup vs baseline: 1.2438x; 1.2438x over previous
//
#include <hip/hip_runtime.h>

typedef unsigned short u16;
typedef short s16x8 __attribute__((ext_vector_type(8)));   // 8 bf16 bit-patterns
typedef float f32x4 __attribute__((ext_vector_type(4)));

#define DI __device__ __forceinline__

constexpr int N_ = 50000;
constexpr int E_ = 400000;
constexpr int G_ = 64;
constexpr int MS_ = 112;            // msg row stride in u16 (224 B)

DI u16 f2bf(float f) {
    union { unsigned u; float f; } c; c.f = f;
    unsigned u = c.u;
    u += 0x7fffu + ((u >> 16) & 1u);   // RNE
    return (u16)(u >> 16);
}
DI float bf2f(u16 v) {
    union { unsigned u; float f; } c; c.u = (unsigned)v << 16;
    return c.f;
}
DI unsigned pkbf(float lo, float hi) {   // u32 = bf16(lo) | bf16(hi)<<16 (RNE)
    return (unsigned)f2bf(lo) | ((unsigned)f2bf(hi) << 16);
}

DI s16x8 ldv(const u16* p) { return *(const s16x8*)p; }
DI f32x4 MFMA(s16x8 a, s16x8 b, f32x4 c) {
    return __builtin_amdgcn_mfma_f32_16x16x32_bf16(a, b, c, 0, 0, 0);
}

// ---------------------------------------------------------------------------
// C-frag pair (transposed GEMM output: rows=channels, cols=edges) -> next
// GEMM's B-frag (lane&15=edge, k=kq*8+j), fused ReLU. Source lane (col,kq)
// holds H[ch=cb*16+kq*4+r][edge=col]; target lane (col',kq') needs channels
// kq'*8+j of edge col'. 8 pkbf + 8 ds_bpermute + 4 selects, no LDS storage.
// Verified case-by-case against C/D layout col=lane&15,row=kq*4+r (m89).
// ---------------------------------------------------------------------------
DI s16x8 conv_frag(const f32x4 a0, const f32x4 a1, int kq, int col) {
    unsigned c0 = pkbf(fmaxf(a0[0], 0.f), fmaxf(a0[1], 0.f));
    unsigned c1 = pkbf(fmaxf(a0[2], 0.f), fmaxf(a0[3], 0.f));
    unsigned c2 = pkbf(fmaxf(a1[0], 0.f), fmaxf(a1[1], 0.f));
    unsigned c3 = pkbf(fmaxf(a1[2], 0.f), fmaxf(a1[3], 0.f));
    int aA = (kq & 1) * 128 + col * 4;       // src lane (kq&1)*32 + col
    int aB = aA + 64;                        // src lane (kq&1)*32 + 16 + col
    unsigned A0 = __builtin_amdgcn_ds_bpermute(aA, (int)c0);
    unsigned A1 = __builtin_amdgcn_ds_bpermute(aA, (int)c1);
    unsigned A2 = __builtin_amdgcn_ds_bpermute(aA, (int)c2);
    unsigned A3 = __builtin_amdgcn_ds_bpermute(aA, (int)c3);
    unsigned B0 = __builtin_amdgcn_ds_bpermute(aB, (int)c0);
    unsigned B1 = __builtin_amdgcn_ds_bpermute(aB, (int)c1);
    unsigned B2 = __builtin_amdgcn_ds_bpermute(aB, (int)c2);
    unsigned B3 = __builtin_amdgcn_ds_bpermute(aB, (int)c3);
    bool hi = (kq >> 1) != 0;
    union { unsigned u[4]; s16x8 v; } o;
    o.u[0] = hi ? A2 : A0;
    o.u[1] = hi ? A3 : A1;
    o.u[2] = hi ? B2 : B0;
    o.u[3] = hi ? B3 : B1;
    return o.v;
}

// ---------------------------------------------------------------------------
// Named kernel: zero hist + repack weights f32 -> bf16 in MFMA-FRAGMENT-
// ORDER TILES (fragoff = col*32 + kq*8), folding
//   [xi, xj-xi] @ W = xi @ (W_a - W_b) + xj @ W_b,
// and BIASES into unused K-pad rows (input slot := 1.0):
//   wt0 k=15 := B1 ; wt1 k=100 := B1 ; wt2 k=300 := B2 ; wt3 k=300 := B3.
// ---------------------------------------------------------------------------
__global__ __launch_bounds__(256)
void ModelGNN_35304631174019_kernel(
          const float* __restrict__ l0w1, const float* __restrict__ l0w2,
          const float* __restrict__ l0w3, const float* __restrict__ l1w1,
          const float* __restrict__ l1w2, const float* __restrict__ l1w3,
          const float* __restrict__ l0b1, const float* __restrict__ l0b2,
          const float* __restrict__ l0b3, const float* __restrict__ l1b1,
          const float* __restrict__ l1b2, const float* __restrict__ l1b3,
          float4* __restrict__ histz,
          u16* __restrict__ wt0, u16* __restrict__ wt1,
          u16* __restrict__ wt2a, u16* __restrict__ wt2b,
          u16* __restrict__ wt3a, u16* __restrict__ wt3b)
{
    int i = blockIdx.x * 256 + threadIdx.x;
    if (i < 12500) { histz[i] = make_float4(0.f, 0.f, 0.f, 0.f); return; }
    int f = i - 12500;

    if (f < 10240) {                       // wt0: layer0 W1, KP=32 (KA=1)
        int sec = f >> 9, w = f & 511;
        int col = w >> 5, rem = w & 31;
        int n0c = sec >> 1, b01 = sec & 1;
        int n = n0c * 32 + b01 * 16 + col, k = rem;
        u16 v = 0;
        if (n < 300) {
            if (k < 7)                  v = f2bf(l0w1[k * 300 + n] - l0w1[(7 + k) * 300 + n]);
            else if (k >= 16 && k < 23) v = f2bf(l0w1[(7 + (k - 16)) * 300 + n]);
            else if (k == 15)           v = f2bf(l0b1[n]);
        }
        wt0[f] = v; return;
    }
    f -= 10240;
    if (f < 71680) {                       // wt1: layer1 W1, KP=224 (KA=7)
        int sec = f >> 9, w = f & 511;
        int col = w >> 5, rem = w & 31;
        int n0c = sec / 14, r = sec % 14;
        int s = r >> 1, b01 = r & 1;
        int n = n0c * 32 + b01 * 16 + col, k = s * 32 + rem;
        u16 v = 0;
        if (n < 300) {
            if (k < 100)                  v = f2bf(l1w1[k * 300 + n] - l1w1[(100 + k) * 300 + n]);
            else if (k >= 112 && k < 212) v = f2bf(l1w1[(100 + (k - 112)) * 300 + n]);
            else if (k == 100)            v = f2bf(l1b1[n]);
        }
        wt1[f] = v; return;
    }
    f -= 71680;
    if (f < 204800) {                      // wt2a / wt2b: 300x300, K=320 (KA=10)
        const float* src = (f < 102400) ? l0w2 : l1w2;
        const float* bia = (f < 102400) ? l0b2 : l1b2;
        u16* dst = (f < 102400) ? wt2a : wt2b;
        int f2 = (f < 102400) ? f : f - 102400;
        int sec = f2 >> 9, w = f2 & 511;
        int col = w >> 5, rem = w & 31;
        int n0c = sec / 20, r = sec % 20;
        int s = r >> 1, b01 = r & 1;
        int n = n0c * 32 + b01 * 16 + col, k = s * 32 + rem;
        u16 v = 0;
        if (n < 300) {
            if (k < 300)       v = f2bf(src[k * 300 + n]);
            else if (k == 300) v = f2bf(bia[n]);
        }
        dst[f2] = v;
        return;
    }
    f -= 204800;
    if (f < 71680) {                       // wt3a / wt3b: 300x100 -> [112 n3][320 k]
        const float* src = (f < 35840) ? l0w3 : l1w3;
        const float* bia = (f < 35840) ? l0b3 : l1b3;
        u16* dst = (f < 35840) ? wt3a : wt3b;
        int f2 = (f < 35840) ? f : f - 35840;
        int sec = f2 >> 9, w = f2 & 511;
        int col = w >> 5, rem = w & 31;
        int ch = sec / 7, u = sec % 7;
        int n3 = u * 16 + col, k = ch * 32 + rem;
        u16 v = 0;
        if (n3 < 100) {
            if (k < 300)       v = f2bf(src[k * 100 + n3]);
            else if (k == 300) v = f2bf(bia[n3]);
        }
        dst[f2] = v;
        return;
    }
}

// ---------------------------------------------------------------------------
// Count-sort edges by dst: hist -> exclusive scan -> scatter-fill.
// pos[d] = run END after fill (start = pos[d-1] or 0) -- used by reduce_k.
// ---------------------------------------------------------------------------
__global__ __launch_bounds__(256)
void hist_k(const int* __restrict__ ei, int* __restrict__ hist)
{
    int i = blockIdx.x * 256 + threadIdx.x;
    if (i < E_) atomicAdd(&hist[ei[E_ + i]], 1);
}

__global__ __launch_bounds__(1024)
void scan_k(int* h)   // in-place exclusive scan of h[50000], single block
{
    __shared__ int part[1024];
    const int t = threadIdx.x;
    const int CH = 49;
    int base = t * CH;
    int end = base + CH; if (end > 50000) end = 50000;
    int s = 0;
    for (int i = base; i < end; ++i) s += h[i];
    part[t] = s;
    __syncthreads();
    for (int d = 1; d < 1024; d <<= 1) {
        int v = (t >= d) ? part[t - d] : 0;
        __syncthreads();
        part[t] += v;
        __syncthreads();
    }
    int run = (t ? part[t - 1] : 0);
    for (int i = base; i < end; ++i) { int c = h[i]; h[i] = run; run += c; }
}

__global__ __launch_bounds__(256)
void fill_k(const int* __restrict__ ei, int* __restrict__ pos, int* __restrict__ sei)
{
    int i = blockIdx.x * 256 + threadIdx.x;
    if (i >= E_) return;
    int s = ei[i], d = ei[E_ + i];
    int p = atomicAdd(&pos[d], 1);
    sei[p] = s; sei[E_ + p] = d;
}

// ---------------------------------------------------------------------------
// edge_mlp R23 = R7 (best: 509us/dispatch, FETCH 230MB -- per-wave weight
// loads stay L2-HOT via temporal reuse; R8-R13 staging variants all paid a
// volume-invariant ~1.3GB L2-miss stream at the ~3TB/s L3 ceiling and lost)
// + BIJECTIVE XCD SWIZZLE (T1/m204): edges are dst-sorted, so consecutive
// blocks gather neighboring agg0 rows + write adjacent msg regions; chunked
// block->XCD mapping makes each XCD's L2 own a contiguous ~2.5MB slice of
// the dst-gather range. Operand-swapped MFMA pipeline, zero in-loop LDS
// transit (conv_frag), biases folded into weight K-pad rows.
// Layouts (m89/m120): A/B: row=lane&15, k=kq*8+j ; C/D: col=lane&15,
// row=kq*4+r (here row=channel, col=edge).
// ---------------------------------------------------------------------------
template<bool FIRST>
__global__ __launch_bounds__(256, 1)
void edge_mlp(const float* __restrict__ X, const float* __restrict__ H0,
              const int* __restrict__ ei,
              const u16* __restrict__ W1, const u16* __restrict__ W2,
              const u16* __restrict__ W3,
              u16* __restrict__ msg)
{
    constexpr int KP = FIRST ? 32 : 224;
    constexpr int KA = KP / 32;
    __shared__ __align__(16) u16 SCR[4 * 32 * MS_];   // 28,672 B (epilogue/gather)

    // bijective XCD swizzle (m204): nwg=3125, q=390, r=5
    const int nwg = (int)gridDim.x;
    const int q = nwg >> 3, r = nwg & 7;
    const int xcd = blockIdx.x & 7, idx = blockIdx.x >> 3;
    const int wg = (xcd < r ? xcd * (q + 1) : r * (q + 1) + (xcd - r) * q) + idx;

    const int tid  = threadIdx.x;
    const int wave = tid >> 6, lane = tid & 63;
    const int col  = lane & 15, kq = lane >> 4;
    const int ebase = wg * 128 + wave * 32;           // 32 edges per wave
    const int fragoff = col * 32 + kq * 8;            // in-section lane offset

    u16* SCw = SCR + wave * (32 * MS_);

    // ---- input fragments (edges as B-operand: row=edge, k=input dim) ----
    s16x8 aF[2][KA];
    if constexpr (FIRST) {
        // gather [xi | 1 | xj] for 32 edges into SCw as bf16 IN[32][40]
        for (int s = lane; s < 32 * 32; s += 64) {
            int e = s >> 5, k = s & 31;
            u16 v = 0;
            if (k < 7)                  v = f2bf(X[(size_t)ei[E_ + ebase + e] * 7 + k]);
            else if (k >= 16 && k < 23) v = f2bf(X[(size_t)ei[ebase + e] * 7 + (k - 16)]);
            else if (k == 15)           v = 0x3f80;   // bias slot: 1.0
            SCw[e * 40 + k] = v;
        }
        #pragma unroll
        for (int rt = 0; rt < 2; ++rt)
            aF[rt][0] = ldv(SCw + (rt * 16 + col) * 40 + kq * 8);
    } else {
        // build fragments from global agg0 (h0, f32 -> bf16), 2 row-tiles
        #pragma unroll
        for (int rt = 0; rt < 2; ++rt) {
            const int dn = ei[E_ + ebase + rt * 16 + col];   // x_i
            const int sn = ei[ebase + rt * 16 + col];        // x_j
            #pragma unroll
            for (int s = 0; s < KA; ++s) {
                int b = s * 4 + kq;                // 8-elem k-group; k = 8b+j
                int node = (b < 14) ? dn : sn;
                int c = ((b < 14) ? b : b - 14) * 8;
                s16x8 t = {0, 0, 0, 0, 0, 0, 0, 0};
                if (c < 104) {
                    const float* r2 = H0 + (size_t)node * 100 + c;
                    float4 lo = *(const float4*)r2;
                    t[0] = (short)f2bf(lo.x); t[1] = (short)f2bf(lo.y);
                    t[2] = (short)f2bf(lo.z); t[3] = (short)f2bf(lo.w);
                    if (c < 96) {
                        float4 hi = *(const float4*)(r2 + 4);
                        t[4] = (short)f2bf(hi.x); t[5] = (short)f2bf(hi.y);
                        t[6] = (short)f2bf(hi.z); t[7] = (short)f2bf(hi.w);
                    }
                }
                if (s == 3 && kq == 0) t[4] = (short)0x3f80;  // k=100 bias slot
                aF[rt][s] = t;
            }
        }
    }

    // ---- GEMM1: H1^T chunks -> in-register conv -> a2 B-fragments ----
    s16x8 a2[2][10];
    #pragma unroll 1
    for (int t2 = 0; t2 < 10; ++t2) {
        const u16* w0 = W1 + (size_t)(t2 * 2 * KA) * 512 + fragoff;
        f32x4 z = {0.f, 0.f, 0.f, 0.f};
        f32x4 ac[2][2] = {{z, z}, {z, z}};            // [cb(ch-half)][rt(edge-half)]
        #pragma unroll
        for (int s = 0; s < KA; ++s) {
            s16x8 b0 = ldv(w0 + (2 * s) * 512);       // contiguous 1 KB wave-load
            s16x8 b1 = ldv(w0 + (2 * s + 1) * 512);
            #pragma unroll
            for (int rt = 0; rt < 2; ++rt) {
                ac[0][rt] = MFMA(b0, aF[rt][s], ac[0][rt]);
                ac[1][rt] = MFMA(b1, aF[rt][s], ac[1][rt]);
            }
        }
        #pragma unroll
        for (int rt = 0; rt < 2; ++rt)
            a2[rt][t2] = conv_frag(ac[0][rt], ac[1][rt], kq, col);
    }
    if (kq == 1) {                                    // GEMM2 k=300 bias slot
        a2[0][9][4] = (short)0x3f80;
        a2[1][9][4] = (short)0x3f80;
    }

    f32x4 mac[2][7];
    #pragma unroll
    for (int rt = 0; rt < 2; ++rt)
        #pragma unroll
        for (int u = 0; u < 7; ++u) { f32x4 z = {0.f, 0.f, 0.f, 0.f}; mac[rt][u] = z; }

    // ---- GEMM2 (K=320) fused with GEMM3 in 32-wide chunks of H2 ----
    #pragma unroll 1
    for (int ch = 0; ch < 10; ++ch) {
        const u16* w0 = W2 + (size_t)(ch * 20) * 512 + fragoff;
        f32x4 z = {0.f, 0.f, 0.f, 0.f};
        f32x4 ac[2][2] = {{z, z}, {z, z}};
        #pragma unroll
        for (int s = 0; s < 10; ++s) {
            s16x8 b0 = ldv(w0 + (2 * s) * 512);       // contiguous 1 KB wave-load
            s16x8 b1 = ldv(w0 + (2 * s + 1) * 512);
            #pragma unroll
            for (int rt = 0; rt < 2; ++rt) {
                ac[0][rt] = MFMA(b0, a2[rt][s], ac[0][rt]);
                ac[1][rt] = MFMA(b1, a2[rt][s], ac[1][rt]);
            }
        }
        s16x8 a3[2];
        #pragma unroll
        for (int rt = 0; rt < 2; ++rt)
            a3[rt] = conv_frag(ac[0][rt], ac[1][rt], kq, col);
        if (ch == 9 && kq == 1) {                     // GEMM3 k=300 bias slot
            a3[0][4] = (short)0x3f80;
            a3[1][4] = (short)0x3f80;
        }
        #pragma unroll
        for (int u = 0; u < 7; ++u) {
            s16x8 b3 = ldv(W3 + (size_t)(ch * 7 + u) * 512 + fragoff);  // 1 KB
            mac[0][u] = MFMA(b3, a3[0], mac[0][u]);
            mac[1][u] = MFMA(b3, a3[1], mac[1][u]);
        }
    }

    // ---- epilogue: mac rows=out-channels, cols=edges. Pack relu'd pairs to
    //      LDS [32 edges][112 ch], then coalesced 16B-lane global stores ----
    #pragma unroll
    for (int rt = 0; rt < 2; ++rt) {
        const int row = rt * 16 + col;
        #pragma unroll
        for (int u = 0; u < 7; ++u) {
            unsigned p0 = pkbf(fmaxf(mac[rt][u][0], 0.f), fmaxf(mac[rt][u][1], 0.f));
            unsigned p1 = pkbf(fmaxf(mac[rt][u][2], 0.f), fmaxf(mac[rt][u][3], 0.f));
            int chb = u * 16 + kq * 4;
            *(unsigned*)(SCw + row * MS_ + chb)     = p0;
            *(unsigned*)(SCw + row * MS_ + chb + 2) = p1;
        }
    }
    // wave-private region: lgkmcnt ordering only
    u16* gdst = msg + (size_t)ebase * MS_;
    #pragma unroll
    for (int q2 = 0; q2 < 7; ++q2) {
        s16x8 v = ldv(SCw + q2 * 512 + lane * 8);
        *(s16x8*)(gdst + q2 * 512 + lane * 8) = v;
    }
}

// ---------------------------------------------------------------------------
// reduce_k: segment-max over sorted msg runs (stride MS_). One wave per node.
// Writes EVERY node (empty run -> 0), so agg needs no zero-init.
// ---------------------------------------------------------------------------
__global__ __launch_bounds__(256)
void reduce_k(const u16* __restrict__ msg, const int* __restrict__ pos,
              float* __restrict__ agg)
{
    const int n = blockIdx.x * 4 + (threadIdx.x >> 6);
    if (n >= N_) return;
    const int lane = threadIdx.x & 63;
    const int start = n ? pos[n - 1] : 0;
    const int end   = pos[n];
    float m0 = 0.f, m1 = 0.f;
    for (int e = start; e < end; ++e) {
        const u16* row = msg + (size_t)e * MS_;
        m0 = fmaxf(m0, bf2f(row[lane]));
        if (lane < 36) m1 = fmaxf(m1, bf2f(row[64 + lane]));
    }
    agg[(size_t)n * 100 + lane] = m0;
    if (lane < 36) agg[(size_t)n * 100 + 64 + lane] = m1;
}

// ---------------------------------------------------------------------------
// pool: one block per graph (batch sorted -> binary-search bounds).
// ---------------------------------------------------------------------------
__global__ __launch_bounds__(256)
void pool(const float* __restrict__ agg1, const int* __restrict__ batch,
          const float* __restrict__ u, float* __restrict__ pooled)
{
    const int g = blockIdx.x;
    int lo = 0, hi = N_;
    while (lo < hi) { int mid = (lo + hi) >> 1; if (batch[mid] < g) lo = mid + 1; else hi = mid; }
    const int start = lo;
    int lo2 = start, hi2 = N_;
    while (lo2 < hi2) { int mid = (lo2 + hi2) >> 1; if (batch[mid] < g + 1) lo2 = mid + 1; else hi2 = mid; }
    const int end = lo2;

    const int c = threadIdx.x & 127, half = threadIdx.x >> 7;
    float sm = 0.f, mx = 0.f;
    if (c < 100)
        for (int n = start + half; n < end; n += 2) {
            float v = agg1[(size_t)n * 100 + c];
            sm += v; mx = fmaxf(mx, v);
        }
    __shared__ float ssum[128], smax[128];
    if (half) { ssum[c] = sm; smax[c] = mx; }
    __syncthreads();
    if (!half && c < 100) {
        sm += ssum[c]; mx = fmaxf(mx, smax[c]);
        int cnt = end - start;
        pooled[g * 302 + c]       = sm;
        pooled[g * 302 + 100 + c] = sm / fmaxf((float)cnt, 1.f);
        pooled[g * 302 + 200 + c] = mx;
    }
    if (threadIdx.x == 0) {
        pooled[g * 302 + 300] = u[g * 2];
        pooled[g * 302 + 301] = u[g * 2 + 1];
    }
}

// ---------------------------------------------------------------------------
// final 302 -> 100 -> 100 -> 2 MLP, one block per graph, fp32
// ---------------------------------------------------------------------------
__global__ __launch_bounds__(128)
void final_mlp(const float* __restrict__ pooled,
               const float* __restrict__ w1, const float* __restrict__ b1,
               const float* __restrict__ w2, const float* __restrict__ b2,
               const float* __restrict__ w3, const float* __restrict__ b3,
               float* __restrict__ out)
{
    const int g = blockIdx.x, t = threadIdx.x;
    __shared__ float P[302], T1[100], T2[100];
    for (int i = t; i < 302; i += 128) P[i] = pooled[g * 302 + i];
    __syncthreads();
    if (t < 100) {
        float a = b1[t];
        for (int i = 0; i < 302; ++i) a = fmaf(P[i], w1[i * 100 + t], a);
        T1[t] = fmaxf(a, 0.f);
    }
    __syncthreads();
    if (t < 100) {
        float a = b2[t];
        for (int i = 0; i < 100; ++i) a = fmaf(T1[i], w2[i * 100 + t], a);
        T2[t] = fmaxf(a, 0.f);
    }
    __syncthreads();
    if (t < 2) {
        float a = b3[t];
        for (int i = 0; i < 100; ++i) a = fmaf(T2[i], w3[i * 2 + t], a);
        out[g * 2 + t] = a;
    }
}

// ---------------------------------------------------------------------------
extern "C" void kernel_launch(void* const* d_in, const int* in_sizes, int n_in,
                              void* d_out, int out_size, void* d_ws, size_t ws_size,
                              hipStream_t stream)
{
    const float* x     = (const float*)d_in[0];
    const int*   ei    = (const int*)d_in[1];
    const int*   batch = (const int*)d_in[2];
    const float* uu    = (const float*)d_in[3];
    const float *l0w1 = (const float*)d_in[4],  *l0b1 = (const float*)d_in[5];
    const float *l0w2 = (const float*)d_in[6],  *l0b2 = (const float*)d_in[7];
    const float *l0w3 = (const float*)d_in[8],  *l0b3 = (const float*)d_in[9];
    const float *l1w1 = (const float*)d_in[10], *l1b1 = (const float*)d_in[11];
    const float *l1w2 = (const float*)d_in[12], *l1b2 = (const float*)d_in[13];
    const float *l1w3 = (const float*)d_in[14], *l1b3 = (const float*)d_in[15];
    const float *lw1  = (const float*)d_in[16], *lb1  = (const float*)d_in[17];
    const float *lw2  = (const float*)d_in[18], *lb2  = (const float*)d_in[19];
    const float *lw3  = (const float*)d_in[20], *lb3  = (const float*)d_in[21];

    char* w = (char*)d_ws;
    float* agg0   = (float*)(w);                    // 20,000,000 B
    float* agg1   = (float*)(w + 20000000);         // 20,000,000 B
    float* pooled = (float*)(w + 40000000);         //     77,312 B
    u16* wt0  = (u16*)(w + 40077312);               //     20,480 B
    u16* wt1  = (u16*)(w + 40097792);               //    143,360 B
    u16* wt2a = (u16*)(w + 40241152);               //    204,800 B
    u16* wt2b = (u16*)(w + 40445952);               //    204,800 B
    u16* wt3a = (u16*)(w + 40650752);               //     71,680 B
    u16* wt3b = (u16*)(w + 40722432);               //     71,680 B
    int* hist = (int*)(w + 40794112);               //    200,000 B (hist -> run ends)
    int* sei  = (int*)(w + 40994112);               //  3,200,000 B (sorted [src|dst])
    u16* msg  = (u16*)(w + 44194112);               // 89,600,000 B (msgs, 224 B rows)
                                                    // total ~127.6 MiB

    ModelGNN_35304631174019_kernel<<<1449, 256, 0, stream>>>(
        l0w1, l0w2, l0w3, l1w1, l1w2, l1w3,
        l0b1, l0b2, l0b3, l1b1, l1b2, l1b3,
        (float4*)hist, wt0, wt1, wt2a, wt2b, wt3a, wt3b);
    hist_k<<<1563, 256, 0, stream>>>(ei, hist);
    scan_k<<<1, 1024, 0, stream>>>(hist);
    fill_k<<<1563, 256, 0, stream>>>(ei, hist, sei);
    edge_mlp<true ><<<3125, 256, 0, stream>>>(x, nullptr, sei, wt0, wt2a, wt3a, msg);
    reduce_k<<<12500, 256, 0, stream>>>(msg, hist, agg0);
    edge_mlp<false><<<3125, 256, 0, stream>>>(nullptr, agg0, sei, wt1, wt2b, wt3b, msg);
    reduce_k<<<12500, 256, 0, stream>>>(msg, hist, agg1);
    pool<<<G_, 256, 0, stream>>>(agg1, batch, uu, pooled);
    final_mlp<<<G_, 128, 0, stream>>>(pooled, lw1, lb1, lw2, lb2, lw3, lb3, (float*)d_out);
}

// Round 16
// 1223.974 us; speedup vs baseline: 1.4062x; 1.1305x over previous
//
#include <hip/hip_runtime.h>

typedef unsigned short u16;
typedef short s16x8 __attribute__((ext_vector_type(8)));   // 8 bf16 bit-patterns
typedef float f32x4 __attribute__((ext_vector_type(4)));

#define DI __device__ __forceinline__

constexpr int N_ = 50000;
constexpr int E_ = 400000;
constexpr int G_ = 64;
constexpr int MS_ = 112;            // msg row stride in u16 (224 B)

DI u16 f2bf(float f) {
    union { unsigned u; float f; } c; c.f = f;
    unsigned u = c.u;
    u += 0x7fffu + ((u >> 16) & 1u);   // RNE
    return (u16)(u >> 16);
}
DI float bf2f(u16 v) {
    union { unsigned u; float f; } c; c.u = (unsigned)v << 16;
    return c.f;
}
DI unsigned pkbf(float lo, float hi) {   // u32 = bf16(lo) | bf16(hi)<<16 (RNE)
    return (unsigned)f2bf(lo) | ((unsigned)f2bf(hi) << 16);
}

DI s16x8 ldv(const u16* p) { return *(const s16x8*)p; }
DI f32x4 MFMA(s16x8 a, s16x8 b, f32x4 c) {
    return __builtin_amdgcn_mfma_f32_16x16x32_bf16(a, b, c, 0, 0, 0);
}

// ---------------------------------------------------------------------------
// C-frag pair (transposed GEMM output: rows=channels, cols=edges) -> next
// GEMM's B-frag (lane&15=edge, k=kq*8+j), fused ReLU. 8 pkbf + 8
// ds_bpermute + 4 selects, no LDS storage. Verified vs C/D layout
// col=lane&15,row=kq*4+r (m89).
// ---------------------------------------------------------------------------
DI s16x8 conv_frag(const f32x4 a0, const f32x4 a1, int kq, int col) {
    unsigned c0 = pkbf(fmaxf(a0[0], 0.f), fmaxf(a0[1], 0.f));
    unsigned c1 = pkbf(fmaxf(a0[2], 0.f), fmaxf(a0[3], 0.f));
    unsigned c2 = pkbf(fmaxf(a1[0], 0.f), fmaxf(a1[1], 0.f));
    unsigned c3 = pkbf(fmaxf(a1[2], 0.f), fmaxf(a1[3], 0.f));
    int aA = (kq & 1) * 128 + col * 4;       // src lane (kq&1)*32 + col
    int aB = aA + 64;                        // src lane (kq&1)*32 + 16 + col
    unsigned A0 = __builtin_amdgcn_ds_bpermute(aA, (int)c0);
    unsigned A1 = __builtin_amdgcn_ds_bpermute(aA, (int)c1);
    unsigned A2 = __builtin_amdgcn_ds_bpermute(aA, (int)c2);
    unsigned A3 = __builtin_amdgcn_ds_bpermute(aA, (int)c3);
    unsigned B0 = __builtin_amdgcn_ds_bpermute(aB, (int)c0);
    unsigned B1 = __builtin_amdgcn_ds_bpermute(aB, (int)c1);
    unsigned B2 = __builtin_amdgcn_ds_bpermute(aB, (int)c2);
    unsigned B3 = __builtin_amdgcn_ds_bpermute(aB, (int)c3);
    bool hi = (kq >> 1) != 0;
    union { unsigned u[4]; s16x8 v; } o;
    o.u[0] = hi ? A2 : A0;
    o.u[1] = hi ? A3 : A1;
    o.u[2] = hi ? B2 : B0;
    o.u[3] = hi ? B3 : B1;
    return o.v;
}

// ---------------------------------------------------------------------------
// Named kernel: zero hist + repack weights f32 -> bf16 in MFMA-FRAGMENT-
// ORDER TILES (fragoff = col*32 + kq*8), folding
//   [xi, xj-xi] @ W = xi @ (W_a - W_b) + xj @ W_b,
// and BIASES into unused K-pad rows (input slot := 1.0):
//   wt0 k=15 := B1 ; wt1 k=100 := B1 ; wt2 k=300 := B2 ; wt3 k=300 := B3.
// ---------------------------------------------------------------------------
__global__ __launch_bounds__(256)
void ModelGNN_35304631174019_kernel(
          const float* __restrict__ l0w1, const float* __restrict__ l0w2,
          const float* __restrict__ l0w3, const float* __restrict__ l1w1,
          const float* __restrict__ l1w2, const float* __restrict__ l1w3,
          const float* __restrict__ l0b1, const float* __restrict__ l0b2,
          const float* __restrict__ l0b3, const float* __restrict__ l1b1,
          const float* __restrict__ l1b2, const float* __restrict__ l1b3,
          float4* __restrict__ histz,
          u16* __restrict__ wt0, u16* __restrict__ wt1,
          u16* __restrict__ wt2a, u16* __restrict__ wt2b,
          u16* __restrict__ wt3a, u16* __restrict__ wt3b)
{
    int i = blockIdx.x * 256 + threadIdx.x;
    if (i < 12500) { histz[i] = make_float4(0.f, 0.f, 0.f, 0.f); return; }
    int f = i - 12500;

    if (f < 10240) {                       // wt0: layer0 W1, KP=32 (KA=1)
        int sec = f >> 9, w = f & 511;
        int col = w >> 5, rem = w & 31;
        int n0c = sec >> 1, b01 = sec & 1;
        int n = n0c * 32 + b01 * 16 + col, k = rem;
        u16 v = 0;
        if (n < 300) {
            if (k < 7)                  v = f2bf(l0w1[k * 300 + n] - l0w1[(7 + k) * 300 + n]);
            else if (k >= 16 && k < 23) v = f2bf(l0w1[(7 + (k - 16)) * 300 + n]);
            else if (k == 15)           v = f2bf(l0b1[n]);
        }
        wt0[f] = v; return;
    }
    f -= 10240;
    if (f < 71680) {                       // wt1: layer1 W1, KP=224 (KA=7)
        int sec = f >> 9, w = f & 511;
        int col = w >> 5, rem = w & 31;
        int n0c = sec / 14, r = sec % 14;
        int s = r >> 1, b01 = r & 1;
        int n = n0c * 32 + b01 * 16 + col, k = s * 32 + rem;
        u16 v = 0;
        if (n < 300) {
            if (k < 100)                  v = f2bf(l1w1[k * 300 + n] - l1w1[(100 + k) * 300 + n]);
            else if (k >= 112 && k < 212) v = f2bf(l1w1[(100 + (k - 112)) * 300 + n]);
            else if (k == 100)            v = f2bf(l1b1[n]);
        }
        wt1[f] = v; return;
    }
    f -= 71680;
    if (f < 204800) {                      // wt2a / wt2b: 300x300, K=320 (KA=10)
        const float* src = (f < 102400) ? l0w2 : l1w2;
        const float* bia = (f < 102400) ? l0b2 : l1b2;
        u16* dst = (f < 102400) ? wt2a : wt2b;
        int f2 = (f < 102400) ? f : f - 102400;
        int sec = f2 >> 9, w = f2 & 511;
        int col = w >> 5, rem = w & 31;
        int n0c = sec / 20, r = sec % 20;
        int s = r >> 1, b01 = r & 1;
        int n = n0c * 32 + b01 * 16 + col, k = s * 32 + rem;
        u16 v = 0;
        if (n < 300) {
            if (k < 300)       v = f2bf(src[k * 300 + n]);
            else if (k == 300) v = f2bf(bia[n]);
        }
        dst[f2] = v;
        return;
    }
    f -= 204800;
    if (f < 71680) {                       // wt3a / wt3b: 300x100 -> [112 n3][320 k]
        const float* src = (f < 35840) ? l0w3 : l1w3;
        const float* bia = (f < 35840) ? l0b3 : l1b3;
        u16* dst = (f < 35840) ? wt3a : wt3b;
        int f2 = (f < 35840) ? f : f - 35840;
        int sec = f2 >> 9, w = f2 & 511;
        int col = w >> 5, rem = w & 31;
        int ch = sec / 7, u = sec % 7;
        int n3 = u * 16 + col, k = ch * 32 + rem;
        u16 v = 0;
        if (n3 < 100) {
            if (k < 300)       v = f2bf(src[k * 100 + n3]);
            else if (k == 300) v = f2bf(bia[n3]);
        }
        dst[f2] = v;
        return;
    }
}

// ---------------------------------------------------------------------------
// Count-sort edges by dst: hist -> exclusive scan -> scatter-fill.
// pos[d] = run END after fill (start = pos[d-1] or 0) -- used by reduce_k.
// ---------------------------------------------------------------------------
__global__ __launch_bounds__(256)
void hist_k(const int* __restrict__ ei, int* __restrict__ hist)
{
    int i = blockIdx.x * 256 + threadIdx.x;
    if (i < E_) atomicAdd(&hist[ei[E_ + i]], 1);
}

__global__ __launch_bounds__(1024)
void scan_k(int* h)   // in-place exclusive scan of h[50000], single block
{
    __shared__ int part[1024];
    const int t = threadIdx.x;
    const int CH = 49;
    int base = t * CH;
    int end = base + CH; if (end > 50000) end = 50000;
    int s = 0;
    for (int i = base; i < end; ++i) s += h[i];
    part[t] = s;
    __syncthreads();
    for (int d = 1; d < 1024; d <<= 1) {
        int v = (t >= d) ? part[t - d] : 0;
        __syncthreads();
        part[t] += v;
        __syncthreads();
    }
    int run = (t ? part[t - 1] : 0);
    for (int i = base; i < end; ++i) { int c = h[i]; h[i] = run; run += c; }
}

__global__ __launch_bounds__(256)
void fill_k(const int* __restrict__ ei, int* __restrict__ pos, int* __restrict__ sei)
{
    int i = blockIdx.x * 256 + threadIdx.x;
    if (i >= E_) return;
    int s = ei[i], d = ei[E_ + i];
    int p = atomicAdd(&pos[d], 1);
    sei[p] = s; sei[E_ + p] = d;
}

// ---------------------------------------------------------------------------
// edge_mlp R25 = R7 + BATCHED WEIGHT LOADS (de-risked: GEMM2 batch split
// into 2 x 10 loads, peak transient 80 VGPR). Diagnosis from R7/R14
// counters: 172K cyc/wave = ~21 serialized L2 round-trips per chunk
// (allocator at 2-waves/SIMD pressure recycles the same few load-dest
// regs -> load->wait->MFMA->load->wait). Fix: explicit fully-static load
// arrays issued BEFORE the MFMA block (1-2 L2 round-trips per chunk) +
// __launch_bounds__(256,1) to permit the VGPRs. Arrays consumed
// immediately -> no R9-style cross-phase spill. Layer-2 H0 gather also
// batched (7 loads per k-half). No swizzle (R14: neutral).
// ---------------------------------------------------------------------------
template<bool FIRST>
__global__ __launch_bounds__(256, 1)
void edge_mlp(const float* __restrict__ X, const float* __restrict__ H0,
              const int* __restrict__ ei,
              const u16* __restrict__ W1, const u16* __restrict__ W2,
              const u16* __restrict__ W3,
              u16* __restrict__ msg)
{
    constexpr int KP = FIRST ? 32 : 224;
    constexpr int KA = KP / 32;
    __shared__ __align__(16) u16 SCR[4 * 32 * MS_];   // 28,672 B (epilogue/gather)

    const int tid  = threadIdx.x;
    const int wave = tid >> 6, lane = tid & 63;
    const int col  = lane & 15, kq = lane >> 4;
    const int ebase = blockIdx.x * 128 + wave * 32;   // 32 edges per wave
    const int fragoff = col * 32 + kq * 8;            // in-section lane offset

    u16* SCw = SCR + wave * (32 * MS_);

    // ---- input fragments (edges as B-operand: row=edge, k=input dim) ----
    s16x8 aF[2][KA];
    if constexpr (FIRST) {
        // gather [xi | 1 | xj] for 32 edges into SCw as bf16 IN[32][40]
        for (int s = lane; s < 32 * 32; s += 64) {
            int e = s >> 5, k = s & 31;
            u16 v = 0;
            if (k < 7)                  v = f2bf(X[(size_t)ei[E_ + ebase + e] * 7 + k]);
            else if (k >= 16 && k < 23) v = f2bf(X[(size_t)ei[ebase + e] * 7 + (k - 16)]);
            else if (k == 15)           v = 0x3f80;   // bias slot: 1.0
            SCw[e * 40 + k] = v;
        }
        #pragma unroll
        for (int rt = 0; rt < 2; ++rt)
            aF[rt][0] = ldv(SCw + (rt * 16 + col) * 40 + kq * 8);
    } else {
        // build fragments from global agg0 (h0, f32 -> bf16), 2 row-tiles.
        // BATCHED: the 14 loads of a row-tile issue before any conversion.
        #pragma unroll
        for (int rt = 0; rt < 2; ++rt) {
            const int dn = ei[E_ + ebase + rt * 16 + col];   // x_i
            const int sn = ei[ebase + rt * 16 + col];        // x_j
            float4 lo[KA], hi[KA];
            #pragma unroll
            for (int s = 0; s < KA; ++s) {
                int b = s * 4 + kq;                // 8-elem k-group; k = 8b+j
                int node = (b < 14) ? dn : sn;
                int c = ((b < 14) ? b : b - 14) * 8;
                const float* r2 = H0 + (size_t)node * 100 + c;
                lo[s] = (c < 104) ? *(const float4*)r2
                                  : make_float4(0.f, 0.f, 0.f, 0.f);
                hi[s] = (c < 96)  ? *(const float4*)(r2 + 4)
                                  : make_float4(0.f, 0.f, 0.f, 0.f);
            }
            #pragma unroll
            for (int s = 0; s < KA; ++s) {
                s16x8 t;
                t[0] = (short)f2bf(lo[s].x); t[1] = (short)f2bf(lo[s].y);
                t[2] = (short)f2bf(lo[s].z); t[3] = (short)f2bf(lo[s].w);
                t[4] = (short)f2bf(hi[s].x); t[5] = (short)f2bf(hi[s].y);
                t[6] = (short)f2bf(hi[s].z); t[7] = (short)f2bf(hi[s].w);
                if (s == 3 && kq == 0) t[4] = (short)0x3f80;  // k=100 bias slot
                aF[rt][s] = t;
            }
        }
    }

    // ---- GEMM1: H1^T chunks -> in-register conv -> a2 B-fragments ----
    s16x8 a2[2][10];
    #pragma unroll 1
    for (int t2 = 0; t2 < 10; ++t2) {
        const u16* w0 = W1 + (size_t)(t2 * 2 * KA) * 512 + fragoff;
        s16x8 wb[2 * KA];                             // batched chunk loads
        #pragma unroll
        for (int s = 0; s < 2 * KA; ++s) wb[s] = ldv(w0 + s * 512);
        f32x4 z = {0.f, 0.f, 0.f, 0.f};
        f32x4 ac[2][2] = {{z, z}, {z, z}};            // [cb(ch-half)][rt(edge-half)]
        #pragma unroll
        for (int s = 0; s < KA; ++s)
            #pragma unroll
            for (int rt = 0; rt < 2; ++rt) {
                ac[0][rt] = MFMA(wb[2 * s],     aF[rt][s], ac[0][rt]);
                ac[1][rt] = MFMA(wb[2 * s + 1], aF[rt][s], ac[1][rt]);
            }
        #pragma unroll
        for (int rt = 0; rt < 2; ++rt)
            a2[rt][t2] = conv_frag(ac[0][rt], ac[1][rt], kq, col);
    }
    if (kq == 1) {                                    // GEMM2 k=300 bias slot
        a2[0][9][4] = (short)0x3f80;
        a2[1][9][4] = (short)0x3f80;
    }

    f32x4 mac[2][7];
    #pragma unroll
    for (int rt = 0; rt < 2; ++rt)
        #pragma unroll
        for (int u = 0; u < 7; ++u) { f32x4 z = {0.f, 0.f, 0.f, 0.f}; mac[rt][u] = z; }

    // ---- GEMM2 (K=320) fused with GEMM3 in 32-wide chunks of H2 ----
    #pragma unroll 1
    for (int ch = 0; ch < 10; ++ch) {
        const u16* w0 = W2 + (size_t)(ch * 20) * 512 + fragoff;
        f32x4 z = {0.f, 0.f, 0.f, 0.f};
        f32x4 ac[2][2] = {{z, z}, {z, z}};
        {   // first half: 10 batched loads, then 20 MFMA
            s16x8 wb[10];
            #pragma unroll
            for (int s = 0; s < 10; ++s) wb[s] = ldv(w0 + s * 512);
            #pragma unroll
            for (int s = 0; s < 5; ++s)
                #pragma unroll
                for (int rt = 0; rt < 2; ++rt) {
                    ac[0][rt] = MFMA(wb[2 * s],     a2[rt][s], ac[0][rt]);
                    ac[1][rt] = MFMA(wb[2 * s + 1], a2[rt][s], ac[1][rt]);
                }
        }
        {   // second half: 10 batched loads, then 20 MFMA
            s16x8 wb[10];
            #pragma unroll
            for (int s = 0; s < 10; ++s) wb[s] = ldv(w0 + (10 + s) * 512);
            #pragma unroll
            for (int s = 0; s < 5; ++s)
                #pragma unroll
                for (int rt = 0; rt < 2; ++rt) {
                    ac[0][rt] = MFMA(wb[2 * s],     a2[rt][5 + s], ac[0][rt]);
                    ac[1][rt] = MFMA(wb[2 * s + 1], a2[rt][5 + s], ac[1][rt]);
                }
        }
        // issue W3 loads before conv_frag (overlap bpermute latency)
        s16x8 w3b[7];
        #pragma unroll
        for (int u = 0; u < 7; ++u)
            w3b[u] = ldv(W3 + (size_t)(ch * 7 + u) * 512 + fragoff);
        s16x8 a3[2];
        #pragma unroll
        for (int rt = 0; rt < 2; ++rt)
            a3[rt] = conv_frag(ac[0][rt], ac[1][rt], kq, col);
        if (ch == 9 && kq == 1) {                     // GEMM3 k=300 bias slot
            a3[0][4] = (short)0x3f80;
            a3[1][4] = (short)0x3f80;
        }
        #pragma unroll
        for (int u = 0; u < 7; ++u) {
            mac[0][u] = MFMA(w3b[u], a3[0], mac[0][u]);
            mac[1][u] = MFMA(w3b[u], a3[1], mac[1][u]);
        }
    }

    // ---- epilogue: mac rows=out-channels, cols=edges. Pack relu'd pairs to
    //      LDS [32 edges][112 ch], then coalesced 16B-lane global stores ----
    #pragma unroll
    for (int rt = 0; rt < 2; ++rt) {
        const int row = rt * 16 + col;
        #pragma unroll
        for (int u = 0; u < 7; ++u) {
            unsigned p0 = pkbf(fmaxf(mac[rt][u][0], 0.f), fmaxf(mac[rt][u][1], 0.f));
            unsigned p1 = pkbf(fmaxf(mac[rt][u][2], 0.f), fmaxf(mac[rt][u][3], 0.f));
            int chb = u * 16 + kq * 4;
            *(unsigned*)(SCw + row * MS_ + chb)     = p0;
            *(unsigned*)(SCw + row * MS_ + chb + 2) = p1;
        }
    }
    // wave-private region: lgkmcnt ordering only
    u16* gdst = msg + (size_t)ebase * MS_;
    #pragma unroll
    for (int q2 = 0; q2 < 7; ++q2) {
        s16x8 v = ldv(SCw + q2 * 512 + lane * 8);
        *(s16x8*)(gdst + q2 * 512 + lane * 8) = v;
    }
}

// ---------------------------------------------------------------------------
// reduce_k: segment-max over sorted msg runs (stride MS_). One wave per node.
// Writes EVERY node (empty run -> 0), so agg needs no zero-init.
// ---------------------------------------------------------------------------
__global__ __launch_bounds__(256)
void reduce_k(const u16* __restrict__ msg, const int* __restrict__ pos,
              float* __restrict__ agg)
{
    const int n = blockIdx.x * 4 + (threadIdx.x >> 6);
    if (n >= N_) return;
    const int lane = threadIdx.x & 63;
    const int start = n ? pos[n - 1] : 0;
    const int end   = pos[n];
    float m0 = 0.f, m1 = 0.f;
    for (int e = start; e < end; ++e) {
        const u16* row = msg + (size_t)e * MS_;
        m0 = fmaxf(m0, bf2f(row[lane]));
        if (lane < 36) m1 = fmaxf(m1, bf2f(row[64 + lane]));
    }
    agg[(size_t)n * 100 + lane] = m0;
    if (lane < 36) agg[(size_t)n * 100 + 64 + lane] = m1;
}

// ---------------------------------------------------------------------------
// pool: one block per graph (batch sorted -> binary-search bounds).
// ---------------------------------------------------------------------------
__global__ __launch_bounds__(256)
void pool(const float* __restrict__ agg1, const int* __restrict__ batch,
          const float* __restrict__ u, float* __restrict__ pooled)
{
    const int g = blockIdx.x;
    int lo = 0, hi = N_;
    while (lo < hi) { int mid = (lo + hi) >> 1; if (batch[mid] < g) lo = mid + 1; else hi = mid; }
    const int start = lo;
    int lo2 = start, hi2 = N_;
    while (lo2 < hi2) { int mid = (lo2 + hi2) >> 1; if (batch[mid] < g + 1) lo2 = mid + 1; else hi2 = mid; }
    const int end = lo2;

    const int c = threadIdx.x & 127, half = threadIdx.x >> 7;
    float sm = 0.f, mx = 0.f;
    if (c < 100)
        for (int n = start + half; n < end; n += 2) {
            float v = agg1[(size_t)n * 100 + c];
            sm += v; mx = fmaxf(mx, v);
        }
    __shared__ float ssum[128], smax[128];
    if (half) { ssum[c] = sm; smax[c] = mx; }
    __syncthreads();
    if (!half && c < 100) {
        sm += ssum[c]; mx = fmaxf(mx, smax[c]);
        int cnt = end - start;
        pooled[g * 302 + c]       = sm;
        pooled[g * 302 + 100 + c] = sm / fmaxf((float)cnt, 1.f);
        pooled[g * 302 + 200 + c] = mx;
    }
    if (threadIdx.x == 0) {
        pooled[g * 302 + 300] = u[g * 2];
        pooled[g * 302 + 301] = u[g * 2 + 1];
    }
}

// ---------------------------------------------------------------------------
// final 302 -> 100 -> 100 -> 2 MLP, one block per graph, fp32
// ---------------------------------------------------------------------------
__global__ __launch_bounds__(128)
void final_mlp(const float* __restrict__ pooled,
               const float* __restrict__ w1, const float* __restrict__ b1,
               const float* __restrict__ w2, const float* __restrict__ b2,
               const float* __restrict__ w3, const float* __restrict__ b3,
               float* __restrict__ out)
{
    const int g = blockIdx.x, t = threadIdx.x;
    __shared__ float P[302], T1[100], T2[100];
    for (int i = t; i < 302; i += 128) P[i] = pooled[g * 302 + i];
    __syncthreads();
    if (t < 100) {
        float a = b1[t];
        for (int i = 0; i < 302; ++i) a = fmaf(P[i], w1[i * 100 + t], a);
        T1[t] = fmaxf(a, 0.f);
    }
    __syncthreads();
    if (t < 100) {
        float a = b2[t];
        for (int i = 0; i < 100; ++i) a = fmaf(T1[i], w2[i * 100 + t], a);
        T2[t] = fmaxf(a, 0.f);
    }
    __syncthreads();
    if (t < 2) {
        float a = b3[t];
        for (int i = 0; i < 100; ++i) a = fmaf(T2[i], w3[i * 2 + t], a);
        out[g * 2 + t] = a;
    }
}

// ---------------------------------------------------------------------------
extern "C" void kernel_launch(void* const* d_in, const int* in_sizes, int n_in,
                              void* d_out, int out_size, void* d_ws, size_t ws_size,
                              hipStream_t stream)
{
    const float* x     = (const float*)d_in[0];
    const int*   ei    = (const int*)d_in[1];
    const int*   batch = (const int*)d_in[2];
    const float* uu    = (const float*)d_in[3];
    const float *l0w1 = (const float*)d_in[4],  *l0b1 = (const float*)d_in[5];
    const float *l0w2 = (const float*)d_in[6],  *l0b2 = (const float*)d_in[7];
    const float *l0w3 = (const float*)d_in[8],  *l0b3 = (const float*)d_in[9];
    const float *l1w1 = (const float*)d_in[10], *l1b1 = (const float*)d_in[11];
    const float *l1w2 = (const float*)d_in[12], *l1b2 = (const float*)d_in[13];
    const float *l1w3 = (const float*)d_in[14], *l1b3 = (const float*)d_in[15];
    const float *lw1  = (const float*)d_in[16], *lb1  = (const float*)d_in[17];
    const float *lw2  = (const float*)d_in[18], *lb2  = (const float*)d_in[19];
    const float *lw3  = (const float*)d_in[20], *lb3  = (const float*)d_in[21];

    char* w = (char*)d_ws;
    float* agg0   = (float*)(w);                    // 20,000,000 B
    float* agg1   = (float*)(w + 20000000);         // 20,000,000 B
    float* pooled = (float*)(w + 40000000);         //     77,312 B
    u16* wt0  = (u16*)(w + 40077312);               //     20,480 B
    u16* wt1  = (u16*)(w + 40097792);               //    143,360 B
    u16* wt2a = (u16*)(w + 40241152);               //    204,800 B
    u16* wt2b = (u16*)(w + 40445952);               //    204,800 B
    u16* wt3a = (u16*)(w + 40650752);               //     71,680 B
    u16* wt3b = (u16*)(w + 40722432);               //     71,680 B
    int* hist = (int*)(w + 40794112);               //    200,000 B (hist -> run ends)
    int* sei  = (int*)(w + 40994112);               //  3,200,000 B (sorted [src|dst])
    u16* msg  = (u16*)(w + 44194112);               // 89,600,000 B (msgs, 224 B rows)
                                                    // total ~127.6 MiB

    ModelGNN_35304631174019_kernel<<<1449, 256, 0, stream>>>(
        l0w1, l0w2, l0w3, l1w1, l1w2, l1w3,
        l0b1, l0b2, l0b3, l1b1, l1b2, l1b3,
        (float4*)hist, wt0, wt1, wt2a, wt2b, wt3a, wt3b);
    hist_k<<<1563, 256, 0, stream>>>(ei, hist);
    scan_k<<<1, 1024, 0, stream>>>(hist);
    fill_k<<<1563, 256, 0, stream>>>(ei, hist, sei);
    edge_mlp<true ><<<3125, 256, 0, stream>>>(x, nullptr, sei, wt0, wt2a, wt3a, msg);
    reduce_k<<<12500, 256, 0, stream>>>(msg, hist, agg0);
    edge_mlp<false><<<3125, 256, 0, stream>>>(nullptr, agg0, sei, wt1, wt2b, wt3b, msg);
    reduce_k<<<12500, 256, 0, stream>>>(msg, hist, agg1);
    pool<<<G_, 256, 0, stream>>>(agg1, batch, uu, pooled);
    final_mlp<<<G_, 128, 0, stream>>>(pooled, lw1, lb1, lw2, lb2, lw3, lb3, (float*)d_out);
}